// Round 2
// baseline (99.158 us; speedup 1.0000x reference)
//
#include <hip/hip_runtime.h>

// Problem: B=4, N=1024, H=64.
// d_out: [0..262143] updated (b,i,d) fp32 ; [262144..4456447] attn (b,i,j) fp32
#define ATTN_OFF 262144

// ws float-slot offsets (1 slot = 4B):
#define WS_HIP  0          // hiP h2v-packed [b][32 hp][1024 i]  131072 slots
#define WS_HJP  131072     // hjP same                            131072 slots

typedef float4 f4;
typedef _Float16 h2v __attribute__((ext_vector_type(2)));

union F4H { f4 f; h2v h[4]; };
union F2H { float2 f; h2v h[2]; };

__device__ __forceinline__ f4 ld4(const float* p) { return *reinterpret_cast<const f4*>(p); }
__device__ __forceinline__ void st4(float* p, f4 v) { *reinterpret_cast<f4*>(p) = v; }
__device__ __forceinline__ float fdot2f(h2v a, h2v b, float c) {
    return __builtin_amdgcn_fdot2(a, b, c, false);   // v_dot2_f32_f16
}
__device__ __forceinline__ h2v pack2(float a, float b) {
    h2v r; r.x = (_Float16)a; r.y = (_Float16)b; return r;
}

// ---------------- Kernel A: hi' = x@W1a^T + b1 (z=0) ; hj = x@W1b^T (z=1).
// fp16 channel-pair packed out. grid (32 iT, 4 b, 2 z) = 256 blocks (full GPU).
__global__ __launch_bounds__(256, 4)
void ka_proj(const float* __restrict__ x, const float* __restrict__ W1,
             const float* __restrict__ b1,
             h2v* __restrict__ hiP, h2v* __restrict__ hjP) {
    __shared__ float xT[64 * 36];   // xT[d][i], 32 rows, pad 36
    __shared__ float w1T[64 * 68];  // w1T[d][c] = W1[c][z*64+d]
    const int t  = threadIdx.x;
    const int i0 = blockIdx.x * 32;
    const int b  = blockIdx.y;
    const int z  = blockIdx.z;
    const int lo = t & 15;
    const int dq = t >> 4;
#pragma unroll
    for (int p = 0; p < 2; ++p) {
        const int il = p * 16 + lo;
        f4 v = ld4(&x[(size_t)(b * 1024 + i0 + il) * 64 + dq * 4]);
        xT[(dq * 4 + 0) * 36 + il] = v.x;
        xT[(dq * 4 + 1) * 36 + il] = v.y;
        xT[(dq * 4 + 2) * 36 + il] = v.z;
        xT[(dq * 4 + 3) * 36 + il] = v.w;
    }
#pragma unroll
    for (int p = 0; p < 4; ++p) {
        const int cl = p * 16 + lo;
        f4 w = ld4(&W1[(size_t)cl * 128 + z * 64 + dq * 4]);
        w1T[(dq * 4 + 0) * 68 + cl] = w.x;
        w1T[(dq * 4 + 1) * 68 + cl] = w.y;
        w1T[(dq * 4 + 2) * 68 + cl] = w.z;
        w1T[(dq * 4 + 3) * 68 + cl] = w.w;
    }
    __syncthreads();
    const int tx = t & 15;   // channel quad
    const int ty = t >> 4;   // i pair
    float acc[2][4];
    if (z == 0) {
        f4 bv = ld4(&b1[tx * 4]);
        acc[0][0] = acc[1][0] = bv.x;
        acc[0][1] = acc[1][1] = bv.y;
        acc[0][2] = acc[1][2] = bv.z;
        acc[0][3] = acc[1][3] = bv.w;
    } else {
#pragma unroll
        for (int ii = 0; ii < 2; ++ii)
#pragma unroll
            for (int cc = 0; cc < 4; ++cc) acc[ii][cc] = 0.f;
    }
#pragma unroll 8
    for (int d = 0; d < 64; ++d) {
        const float2 xv = *reinterpret_cast<const float2*>(&xT[d * 36 + ty * 2]);
        const f4 wv = ld4(&w1T[d * 68 + tx * 4]);
        acc[0][0] = fmaf(xv.x, wv.x, acc[0][0]);
        acc[0][1] = fmaf(xv.x, wv.y, acc[0][1]);
        acc[0][2] = fmaf(xv.x, wv.z, acc[0][2]);
        acc[0][3] = fmaf(xv.x, wv.w, acc[0][3]);
        acc[1][0] = fmaf(xv.y, wv.x, acc[1][0]);
        acc[1][1] = fmaf(xv.y, wv.y, acc[1][1]);
        acc[1][2] = fmaf(xv.y, wv.z, acc[1][2]);
        acc[1][3] = fmaf(xv.y, wv.w, acc[1][3]);
    }
    h2v* outp = z ? hjP : hiP;
#pragma unroll
    for (int p = 0; p < 2; ++p) {
        F2H uo;
        uo.h[0] = pack2(acc[0][p * 2], acc[0][p * 2 + 1]);
        uo.h[1] = pack2(acc[1][p * 2], acc[1][p * 2 + 1]);
        *reinterpret_cast<float2*>(
            &outp[(size_t)(b * 32 + tx * 2 + p) * 1024 + i0 + ty * 2]) = uo.f;
    }
}

// ---------------- Fused kernel: logits (registers) + softmax + attn write + AV + reduce.
// grid (128 iT-of-8-rows, 4 b) = 512 blocks (2/CU), block 256.
// Wave w owns rows {w, w+4}: each hj LDS read serves 2 rows; hi/w2 preloaded
// to registers (hp loop fully unrolled -> static indexing, no scratch).
__global__ __launch_bounds__(256, 2)
void kf_fused(const h2v* __restrict__ hiP, const h2v* __restrict__ hjP,
              const float* __restrict__ W2, const float* __restrict__ x,
              float* __restrict__ attn, float* __restrict__ upd) {
    __shared__ union __align__(16) U {
        h2v   hj[32 * 256];   // phase A chunk: [hp][j]        32 KB
        h2v   xc[128 * 68];   // AV chunk: [jpl][d pad68]      34 KB
        float red[16 * 516];  // cross-js reduction            33 KB
    } u;
    __shared__ __align__(16) h2v s_p[512 * 12];  // [jp][i pad12] e fp16
    __shared__ h2v s_hi[32 * 8];
    __shared__ h2v s_w2[32];
    __shared__ float s_il[8];

    const int t  = threadIdx.x;
    const int i0 = blockIdx.x * 8;
    const int b  = blockIdx.y;
    const int w  = t >> 6;   // wave 0..3 -> rows w, w+4
    const int ln = t & 63;   // lane: j = c*256 + ln*4 .. +3
    {
        const int hp = t >> 3, r = t & 7;
        s_hi[hp * 8 + r] = hiP[(size_t)(b * 32 + hp) * 1024 + i0 + r];
    }
    if (t < 16) {
        f4 wq = ld4(&W2[t * 4]);
        s_w2[t * 2]     = pack2(wq.x, wq.y);
        s_w2[t * 2 + 1] = pack2(wq.z, wq.w);
    }
    float l[2][4][4];
#pragma unroll
    for (int r = 0; r < 2; ++r)
#pragma unroll
        for (int c = 0; c < 4; ++c)
#pragma unroll
            for (int k = 0; k < 4; ++k) l[r][c][k] = 0.f;
    h2v hiR[2][32], w2R[32];
    const h2v z2 = (h2v)0;
    // -------- phase A: logits in registers, hj streamed via LDS, 2 rows/thread
#pragma unroll
    for (int c = 0; c < 4; ++c) {
#pragma unroll
        for (int p = 0; p < 8; ++p) {
            const int s = p * 256 + t;
            const int hp = s >> 6, j4 = (s & 63) * 4;
            st4((float*)&u.hj[hp * 256 + j4],
                ld4((const float*)&hjP[(size_t)(b * 32 + hp) * 1024 + c * 256 + j4]));
        }
        __syncthreads();
        if (c == 0) {   // one-time broadcast preload (after s_hi/s_w2 visible)
#pragma unroll
            for (int hp = 0; hp < 32; ++hp) {
                hiR[0][hp] = s_hi[hp * 8 + w];
                hiR[1][hp] = s_hi[hp * 8 + w + 4];
                w2R[hp]    = s_w2[hp];
            }
        }
#pragma unroll
        for (int hp = 0; hp < 32; ++hp) {
            F4H bb;
            bb.f = ld4((const float*)&u.hj[hp * 256 + ln * 4]);
            const h2v wv = w2R[hp];
#pragma unroll
            for (int r = 0; r < 2; ++r) {
                const h2v hv = hiR[r][hp];
#pragma unroll
                for (int k = 0; k < 4; ++k) {
                    h2v rr = __builtin_elementwise_max(hv + bb.h[k], z2);
                    l[r][c][k] = fdot2f(rr, wv, l[r][c][k]);
                }
            }
        }
        __syncthreads();
    }
    // -------- softmax: each row owned by one full wave (64 lanes x 16 logits)
    float il[2];
#pragma unroll
    for (int r = 0; r < 2; ++r) {
        float m = l[r][0][0];
#pragma unroll
        for (int c = 0; c < 4; ++c)
#pragma unroll
            for (int k = 0; k < 4; ++k) m = fmaxf(m, l[r][c][k]);
#pragma unroll
        for (int d = 1; d < 64; d <<= 1) m = fmaxf(m, __shfl_xor(m, d));
        float sum = 0.f;
#pragma unroll
        for (int c = 0; c < 4; ++c)
#pragma unroll
            for (int k = 0; k < 4; ++k) {
                l[r][c][k] = __expf(l[r][c][k] - m);
                sum += l[r][c][k];
            }
#pragma unroll
        for (int d = 1; d < 64; d <<= 1) sum += __shfl_xor(sum, d);
        il[r] = 1.0f / sum;
    }
    if (ln == 0) { s_il[w] = il[0]; s_il[w + 4] = il[1]; }
    // -------- attn write (fp32 from regs) + fp16 e pack to s_p
#pragma unroll
    for (int r = 0; r < 2; ++r) {
        const int row = w + r * 4;
        const size_t arow = (size_t)(b * 1024 + i0 + row) * 1024 + ln * 4;
#pragma unroll
        for (int c = 0; c < 4; ++c) {
            st4(&attn[arow + c * 256],
                make_float4(l[r][c][0] * il[r], l[r][c][1] * il[r],
                            l[r][c][2] * il[r], l[r][c][3] * il[r]));
            const int jp = c * 128 + ln * 2;
            s_p[jp * 12 + row]       = pack2(l[r][c][0], l[r][c][1]);
            s_p[(jp + 1) * 12 + row] = pack2(l[r][c][2], l[r][c][3]);
        }
    }
    // -------- AV: acc[i][d] += e * x, dot2 over j-pairs, x streamed via LDS
    const int dq = t & 15, js = t >> 4;
    float acc[8][4];
#pragma unroll
    for (int i = 0; i < 8; ++i)
#pragma unroll
        for (int q = 0; q < 4; ++q) acc[i][q] = 0.f;
#pragma unroll
    for (int c2 = 0; c2 < 4; ++c2) {
        __syncthreads();   // s_p ready (1st iter) / prev xc reads done
#pragma unroll
        for (int p = 0; p < 8; ++p) {
            const int s = p * 256 + t;
            const int jpl = s >> 4, dd = (s & 15) * 4;
            const float* xr = &x[(size_t)(b * 1024 + c2 * 256 + jpl * 2) * 64 + dd];
            f4 r0 = ld4(xr);
            f4 r1 = ld4(xr + 64);
            F4H pk;
            pk.h[0] = pack2(r0.x, r1.x); pk.h[1] = pack2(r0.y, r1.y);
            pk.h[2] = pack2(r0.z, r1.z); pk.h[3] = pack2(r0.w, r1.w);
            st4((float*)&u.xc[jpl * 68 + dd], pk.f);
        }
        __syncthreads();
#pragma unroll 2
        for (int u8 = 0; u8 < 8; ++u8) {
            const int jpl = u8 * 16 + js;
            const int jp  = c2 * 128 + jpl;
            F4H p0, p1, xv;
            p0.f = ld4((const float*)&s_p[jp * 12]);       // i 0..3
            p1.f = ld4((const float*)&s_p[jp * 12 + 4]);   // i 4..7
            xv.f = ld4((const float*)&u.xc[jpl * 68 + dq * 4]);
#pragma unroll
            for (int i = 0; i < 8; ++i) {
                const h2v pa = (i < 4) ? p0.h[i] : p1.h[i - 4];
#pragma unroll
                for (int q = 0; q < 4; ++q)
                    acc[i][q] = fdot2f(pa, xv.h[q], acc[i][q]);
            }
        }
    }
    // -------- cross-js reduction in LDS (reuse union region) + scaled output
    __syncthreads();
#pragma unroll
    for (int i = 0; i < 8; ++i)
        st4(&u.red[js * 516 + i * 64 + dq * 4],
            make_float4(acc[i][0], acc[i][1], acc[i][2], acc[i][3]));
    __syncthreads();
    if (t < 128) {
        const int i = t >> 4, dqq = t & 15;
        f4 a = ld4(&u.red[i * 64 + dqq * 4]);
#pragma unroll
        for (int js2 = 1; js2 < 16; ++js2) {
            f4 v = ld4(&u.red[js2 * 516 + i * 64 + dqq * 4]);
            a.x += v.x; a.y += v.y; a.z += v.z; a.w += v.w;
        }
        const float sc = s_il[i];
        st4(&upd[(size_t)(b * 1024 + i0 + i) * 64 + dqq * 4],
            make_float4(a.x * sc, a.y * sc, a.z * sc, a.w * sc));
    }
}

extern "C" void kernel_launch(void* const* d_in, const int* in_sizes, int n_in,
                              void* d_out, int out_size, void* d_ws, size_t ws_size,
                              hipStream_t stream) {
    const float* x  = (const float*)d_in[0];
    const float* W1 = (const float*)d_in[1];
    const float* b1 = (const float*)d_in[2];
    const float* W2 = (const float*)d_in[3];
    // d_in[4] = b2: softmax shift-invariance -> unused.
    float* out = (float*)d_out;
    float* ws  = (float*)d_ws;
    h2v* hiP = (h2v*)(ws + WS_HIP);
    h2v* hjP = (h2v*)(ws + WS_HJP);

    ka_proj <<<dim3(32, 4, 2), 256, 0, stream>>>(x, W1, b1, hiP, hjP);
    kf_fused<<<dim3(128, 4),   256, 0, stream>>>(hiP, hjP, W2, x, out + ATTN_OFF, out);
}

// Round 4
// 95.562 us; speedup vs baseline: 1.0376x; 1.0376x over previous
//
#include <hip/hip_runtime.h>

// Problem: B=4, N=1024, H=64.
// d_out: [0..262143] updated (b,i,d) fp32 ; [262144..4456447] attn (b,i,j) fp32
#define ATTN_OFF 262144

// ws float-slot offsets (1 slot = 4B):
#define WS_HIT  0          // hiT h2v-packed [b][1024 i][32 hp]  131072 slots
#define WS_HJP  131072     // hjP h2v-packed [b][32 hp][1024 j]  131072 slots
#define WS_W2P  262144     // w2P h2v[32]                        64 slots

typedef float4 f4;
typedef _Float16 h2v __attribute__((ext_vector_type(2)));

union F4H { f4 f; h2v h[4]; };
union F2H { float2 f; h2v h[2]; };

__device__ __forceinline__ f4 ld4(const float* p) { return *reinterpret_cast<const f4*>(p); }
__device__ __forceinline__ void st4(float* p, f4 v) { *reinterpret_cast<f4*>(p) = v; }
__device__ __forceinline__ float fdot2f(h2v a, h2v b, float c) {
    return __builtin_amdgcn_fdot2(a, b, c, false);   // v_dot2_f32_f16
}
__device__ __forceinline__ h2v pack2(float a, float b) {
    h2v r; r.x = (_Float16)a; r.y = (_Float16)b; return r;
}

// ---------------- Kernel A: hi' = x@W1a^T + b1 -> hiT[b][i][hp] (z=0);
//                  hj = x@W1b^T -> hjP[b][hp][j] (z=1). Also packs w2P.
// grid (32 iT, 4 b, 2 z) = 256 blocks.
__global__ __launch_bounds__(256, 4)
void ka_proj(const float* __restrict__ x, const float* __restrict__ W1,
             const float* __restrict__ b1, const float* __restrict__ W2,
             h2v* __restrict__ hiT, h2v* __restrict__ hjP, h2v* __restrict__ w2P) {
    __shared__ float xT[64 * 36];   // xT[d][i], 32 rows, pad 36
    __shared__ float w1T[64 * 68];  // w1T[d][c] = W1[c][z*64+d]
    const int t  = threadIdx.x;
    const int i0 = blockIdx.x * 32;
    const int b  = blockIdx.y;
    const int z  = blockIdx.z;
    const int lo = t & 15;
    const int dq = t >> 4;
    if (z == 0 && blockIdx.x == 0 && b == 0 && t < 16) {
        f4 wq = ld4(&W2[t * 4]);
        w2P[t * 2]     = pack2(wq.x, wq.y);
        w2P[t * 2 + 1] = pack2(wq.z, wq.w);
    }
#pragma unroll
    for (int p = 0; p < 2; ++p) {
        const int il = p * 16 + lo;
        f4 v = ld4(&x[(size_t)(b * 1024 + i0 + il) * 64 + dq * 4]);
        xT[(dq * 4 + 0) * 36 + il] = v.x;
        xT[(dq * 4 + 1) * 36 + il] = v.y;
        xT[(dq * 4 + 2) * 36 + il] = v.z;
        xT[(dq * 4 + 3) * 36 + il] = v.w;
    }
#pragma unroll
    for (int p = 0; p < 4; ++p) {
        const int cl = p * 16 + lo;
        f4 w = ld4(&W1[(size_t)cl * 128 + z * 64 + dq * 4]);
        w1T[(dq * 4 + 0) * 68 + cl] = w.x;
        w1T[(dq * 4 + 1) * 68 + cl] = w.y;
        w1T[(dq * 4 + 2) * 68 + cl] = w.z;
        w1T[(dq * 4 + 3) * 68 + cl] = w.w;
    }
    __syncthreads();
    const int tx = t & 15;   // channel quad
    const int ty = t >> 4;   // i pair
    float acc[2][4];
    if (z == 0) {
        f4 bv = ld4(&b1[tx * 4]);
        acc[0][0] = acc[1][0] = bv.x;
        acc[0][1] = acc[1][1] = bv.y;
        acc[0][2] = acc[1][2] = bv.z;
        acc[0][3] = acc[1][3] = bv.w;
    } else {
#pragma unroll
        for (int ii = 0; ii < 2; ++ii)
#pragma unroll
            for (int cc = 0; cc < 4; ++cc) acc[ii][cc] = 0.f;
    }
#pragma unroll 8
    for (int d = 0; d < 64; ++d) {
        const float2 xv = *reinterpret_cast<const float2*>(&xT[d * 36 + ty * 2]);
        const f4 wv = ld4(&w1T[d * 68 + tx * 4]);
        acc[0][0] = fmaf(xv.x, wv.x, acc[0][0]);
        acc[0][1] = fmaf(xv.x, wv.y, acc[0][1]);
        acc[0][2] = fmaf(xv.x, wv.z, acc[0][2]);
        acc[0][3] = fmaf(xv.x, wv.w, acc[0][3]);
        acc[1][0] = fmaf(xv.y, wv.x, acc[1][0]);
        acc[1][1] = fmaf(xv.y, wv.y, acc[1][1]);
        acc[1][2] = fmaf(xv.y, wv.z, acc[1][2]);
        acc[1][3] = fmaf(xv.y, wv.w, acc[1][3]);
    }
    if (z == 0) {
        // hiT[b][row][hp]: h2v hp holds channels (2hp, 2hp+1)
#pragma unroll
        for (int ii = 0; ii < 2; ++ii) {
            F2H uo;
            uo.h[0] = pack2(acc[ii][0], acc[ii][1]);
            uo.h[1] = pack2(acc[ii][2], acc[ii][3]);
            *reinterpret_cast<float2*>(
                &hiT[(size_t)(b * 1024 + i0 + ty * 2 + ii) * 32 + tx * 2]) = uo.f;
        }
    } else {
        // hjP[b][hp][j]
#pragma unroll
        for (int p = 0; p < 2; ++p) {
            F2H uo;
            uo.h[0] = pack2(acc[0][p * 2], acc[0][p * 2 + 1]);
            uo.h[1] = pack2(acc[1][p * 2], acc[1][p * 2 + 1]);
            *reinterpret_cast<float2*>(
                &hjP[(size_t)(b * 32 + tx * 2 + p) * 1024 + i0 + ty * 2]) = uo.f;
        }
    }
}

// ---------------- Fused kernel: logits (registers) + softmax + attn write + AV + reduce.
// grid (128 iT-of-8-rows, 4 b) = 512 blocks (2/CU), block 256.
// Wave w owns rows {w, w+4}. hi/w2 preloaded from GLOBAL (not rematerializable).
// hj chunks reg-staged issue-early/write-late. AV reads x direct from L2.
// LDS: 32768 (s_hj) + 24576 (s_p) + 6144 (s_red) + 32 (s_il) = 63520 B. No aliasing.
__global__ __launch_bounds__(256, 2)
void kf_fused(const h2v* __restrict__ hiT, const h2v* __restrict__ hjP,
              const h2v* __restrict__ w2P, const float* __restrict__ x,
              float* __restrict__ attn, float* __restrict__ upd) {
    __shared__ __align__(16) h2v s_hj[32 * 256];     // phase-A chunk [hp][j]
    __shared__ __align__(16) h2v s_p[512 * 12];      // [jp][i pad12] e fp16
    __shared__ __align__(16) float s_red[3 * 8 * 64];// waves 1..3 partials
    __shared__ float s_il[8];

    const int t  = threadIdx.x;
    const int i0 = blockIdx.x * 8;
    const int b  = blockIdx.y;
    const int w  = t >> 6;   // wave 0..3 -> rows w, w+4
    const int ln = t & 63;   // lane: j = c*256 + ln*4 .. +3

    // one-time register preloads from global (wave-uniform addresses)
    F4H hiR[2][8], w2R[8];
#pragma unroll
    for (int u = 0; u < 8; ++u) {
        hiR[0][u].f = ld4((const float*)&hiT[(size_t)(b * 1024 + i0 + w) * 32 + u * 4]);
        hiR[1][u].f = ld4((const float*)&hiT[(size_t)(b * 1024 + i0 + w + 4) * 32 + u * 4]);
        w2R[u].f    = ld4((const float*)&w2P[u * 4]);
    }

    float l[2][4][4];
#pragma unroll
    for (int r = 0; r < 2; ++r)
#pragma unroll
        for (int c = 0; c < 4; ++c)
#pragma unroll
            for (int k = 0; k < 4; ++k) l[r][c][k] = 0.f;
    const h2v z2 = (h2v)0;

    // -------- phase A: reg-staged hj chunks (issue-early / write-late)
    f4 G[8];
#pragma unroll
    for (int p = 0; p < 8; ++p)
        G[p] = ld4((const float*)&hjP[(size_t)(b * 32 + p * 4 + w) * 1024 + ln * 4]);
#pragma unroll
    for (int c = 0; c < 4; ++c) {
#pragma unroll
        for (int p = 0; p < 8; ++p)
            st4((float*)&s_hj[(p * 4 + w) * 256 + ln * 4], G[p]);
        __syncthreads();
        if (c < 3) {
#pragma unroll
            for (int p = 0; p < 8; ++p)
                G[p] = ld4((const float*)&hjP[(size_t)(b * 32 + p * 4 + w) * 1024 +
                                              (c + 1) * 256 + ln * 4]);
        }
#pragma unroll
        for (int hp = 0; hp < 32; ++hp) {
            F4H bb;
            bb.f = ld4((const float*)&s_hj[hp * 256 + ln * 4]);
            const h2v wv = w2R[hp >> 2].h[hp & 3];
#pragma unroll
            for (int r = 0; r < 2; ++r) {
                const h2v hv = hiR[r][hp >> 2].h[hp & 3];
#pragma unroll
                for (int k = 0; k < 4; ++k) {
                    h2v rr = __builtin_elementwise_max(hv + bb.h[k], z2);
                    l[r][c][k] = fdot2f(rr, wv, l[r][c][k]);
                }
            }
        }
        __syncthreads();
    }
    // -------- softmax: each row owned by one full wave (64 lanes x 16 logits)
    float il[2];
#pragma unroll
    for (int r = 0; r < 2; ++r) {
        float m = l[r][0][0];
#pragma unroll
        for (int c = 0; c < 4; ++c)
#pragma unroll
            for (int k = 0; k < 4; ++k) m = fmaxf(m, l[r][c][k]);
#pragma unroll
        for (int d = 1; d < 64; d <<= 1) m = fmaxf(m, __shfl_xor(m, d));
        float sum = 0.f;
#pragma unroll
        for (int c = 0; c < 4; ++c)
#pragma unroll
            for (int k = 0; k < 4; ++k) {
                l[r][c][k] = __expf(l[r][c][k] - m);
                sum += l[r][c][k];
            }
#pragma unroll
        for (int d = 1; d < 64; d <<= 1) sum += __shfl_xor(sum, d);
        il[r] = 1.0f / sum;
    }
    if (ln == 0) { s_il[w] = il[0]; s_il[w + 4] = il[1]; }
    // -------- attn write (fp32 from regs) + fp16 e pack to s_p
#pragma unroll
    for (int r = 0; r < 2; ++r) {
        const int row = w + r * 4;
        const size_t arow = (size_t)(b * 1024 + i0 + row) * 1024 + ln * 4;
#pragma unroll
        for (int c = 0; c < 4; ++c) {
            st4(&attn[arow + c * 256],
                make_float4(l[r][c][0] * il[r], l[r][c][1] * il[r],
                            l[r][c][2] * il[r], l[r][c][3] * il[r]));
            const int jp = c * 128 + ln * 2;
            s_p[jp * 12 + row]       = pack2(l[r][c][0], l[r][c][1]);
            s_p[(jp + 1) * 12 + row] = pack2(l[r][c][2], l[r][c][3]);
        }
    }
    __syncthreads();
    // -------- AV: wave w owns jp in [w*128,(w+1)*128); x read direct (L2-hot)
    const int dq = t & 15, jsl = (t >> 4) & 3;
    float acc[8][4];
#pragma unroll
    for (int i = 0; i < 8; ++i)
#pragma unroll
        for (int q = 0; q < 4; ++q) acc[i][q] = 0.f;
#pragma unroll 4
    for (int it = 0; it < 32; ++it) {
        const int jp = w * 128 + it * 4 + jsl;
        F4H p0, p1, xv;
        p0.f = ld4((const float*)&s_p[jp * 12]);       // i 0..3 (broadcast across dq)
        p1.f = ld4((const float*)&s_p[jp * 12 + 4]);   // i 4..7
        const float* xr = &x[(size_t)(b * 1024 + jp * 2) * 64 + dq * 4];
        f4 r0 = ld4(xr);
        f4 r1 = ld4(xr + 64);
        xv.h[0] = pack2(r0.x, r1.x); xv.h[1] = pack2(r0.y, r1.y);
        xv.h[2] = pack2(r0.z, r1.z); xv.h[3] = pack2(r0.w, r1.w);
#pragma unroll
        for (int i = 0; i < 8; ++i) {
            const h2v pa = (i < 4) ? p0.h[i] : p1.h[i - 4];
#pragma unroll
            for (int q = 0; q < 4; ++q)
                acc[i][q] = fdot2f(pa, xv.h[q], acc[i][q]);
        }
    }
    // wave-level pre-reduce over jsl (lanes ^16, ^32)
#pragma unroll
    for (int i = 0; i < 8; ++i)
#pragma unroll
        for (int q = 0; q < 4; ++q) {
            acc[i][q] += __shfl_xor(acc[i][q], 16);
            acc[i][q] += __shfl_xor(acc[i][q], 32);
        }
    // waves 1..3 store partials; wave 0 keeps in regs and finishes
    if (w > 0 && jsl == 0) {
#pragma unroll
        for (int i = 0; i < 8; ++i)
            st4(&s_red[((w - 1) * 8 + i) * 64 + dq * 4],
                make_float4(acc[i][0], acc[i][1], acc[i][2], acc[i][3]));
    }
    __syncthreads();
    if (w == 0 && jsl == 0) {   // 16 lanes hold the full 8x64 tile
#pragma unroll
        for (int i = 0; i < 8; ++i) {
            f4 a = make_float4(acc[i][0], acc[i][1], acc[i][2], acc[i][3]);
#pragma unroll
            for (int wv2 = 0; wv2 < 3; ++wv2) {
                f4 v = ld4(&s_red[(wv2 * 8 + i) * 64 + dq * 4]);
                a.x += v.x; a.y += v.y; a.z += v.z; a.w += v.w;
            }
            const float sc = s_il[i];
            st4(&upd[(size_t)(b * 1024 + i0 + i) * 64 + dq * 4],
                make_float4(a.x * sc, a.y * sc, a.z * sc, a.w * sc));
        }
    }
}

extern "C" void kernel_launch(void* const* d_in, const int* in_sizes, int n_in,
                              void* d_out, int out_size, void* d_ws, size_t ws_size,
                              hipStream_t stream) {
    const float* x  = (const float*)d_in[0];
    const float* W1 = (const float*)d_in[1];
    const float* b1 = (const float*)d_in[2];
    const float* W2 = (const float*)d_in[3];
    // d_in[4] = b2: softmax shift-invariance -> unused.
    float* out = (float*)d_out;
    float* ws  = (float*)d_ws;
    h2v* hiT = (h2v*)(ws + WS_HIT);
    h2v* hjP = (h2v*)(ws + WS_HJP);
    h2v* w2P = (h2v*)(ws + WS_W2P);

    ka_proj <<<dim3(32, 4, 2), 256, 0, stream>>>(x, W1, b1, W2, hiT, hjP, w2P);
    kf_fused<<<dim3(128, 4),   256, 0, stream>>>(hiT, hjP, w2P, x, out + ATTN_OFF, out);
}